// Round 1
// baseline (2491.229 us; speedup 1.0000x reference)
//
#include <hip/hip_runtime.h>

#define HIDDEN 128
#define OUT_EMB 256
#define NLAYERS 3
#define TM 64
#define LDA 264   // LDS row stride in bf16 elements (256 + 8 pad, keeps 16B align)

typedef __bf16 bf16x8 __attribute__((ext_vector_type(8)));
typedef float f32x4 __attribute__((ext_vector_type(4)));

__device__ __forceinline__ unsigned short f2bf(float x) {
    union { float f; unsigned u; } c; c.f = x;
    unsigned r = c.u + 0x7fff + ((c.u >> 16) & 1);
    return (unsigned short)(r >> 16);
}
__device__ __forceinline__ float bf2f(unsigned short h) {
    union { unsigned u; float f; } c; c.u = ((unsigned)h) << 16;
    return c.f;
}

// ---------------- scatter: v[idx[e]] += e2[e] ----------------
__global__ __launch_bounds__(256) void scatter_kernel(
    const float* __restrict__ e2, const int* __restrict__ idx,
    float* __restrict__ v, int num_edges)
{
    long long j = (long long)blockIdx.x * blockDim.x + threadIdx.x;
    int e = (int)(j >> 5);
    if (e >= num_edges) return;
    int c = (int)(j & 31) << 2;
    const float4 x = *(const float4*)(e2 + (long long)e * HIDDEN + c);
    int n = idx[e];
    float* dst = v + (long long)n * HIDDEN + c;
    atomicAdd(dst + 0, x.x);
    atomicAdd(dst + 1, x.y);
    atomicAdd(dst + 2, x.z);
    atomicAdd(dst + 3, x.w);
}

// ---------------- weight fp32 -> bf16 conversion ----------------
__global__ __launch_bounds__(256) void convert_kernel(
    const float* __restrict__ wup_f, const float* __restrict__ ws_f,
    unsigned short* __restrict__ wup, unsigned short* __restrict__ wsl)
{
    int t = blockIdx.x * blockDim.x + threadIdx.x;
    const int n1 = OUT_EMB * HIDDEN;
    const int n2 = NLAYERS * OUT_EMB * OUT_EMB;
    if (t < n1) wup[t] = f2bf(wup_f[t]);
    else if (t < n1 + n2) wsl[t - n1] = f2bf(ws_f[t - n1]);
}

// ---------------- fused MLP ----------------
// one block = 64 rows; 4 waves; wave w owns rows 16w..16w+15 (wave-private, no barriers)
__global__ __launch_bounds__(256) void mlp_kernel(
    const float* __restrict__ v,
    const unsigned short* __restrict__ wup,   // [256][128] bf16
    const float* __restrict__ bup,            // [256]
    const unsigned short* __restrict__ wsl,   // [3][256][256] bf16
    const float* __restrict__ bs,             // [3][256]
    const float* __restrict__ wout,           // [256] fp32
    float* __restrict__ out, int M)
{
    __shared__ unsigned short act[TM * LDA];

    const int tid  = threadIdx.x;
    const int wv   = tid >> 6;
    const int lane = tid & 63;
    const int m0   = wv * 16;
    const int ln15 = lane & 15;
    const int kq   = lane >> 4;          // 0..3
    const long long rowbase = (long long)blockIdx.x * TM;

    // ---- stage v tile rows m0..m0+15 into LDS (bf16, cols 0..127) ----
    {
        int rsub = lane >> 3;            // 0..7
        int c0f4 = (lane & 7);           // float4 index within 8
        #pragma unroll
        for (int pass = 0; pass < 2; ++pass) {
            int r = m0 + pass * 8 + rsub;
            const float4* src = (const float4*)(v + (rowbase + r) * HIDDEN);
            unsigned short* dst = &act[r * LDA];
            #pragma unroll
            for (int cc = 0; cc < 4; ++cc) {
                float4 x = src[c0f4 + cc * 8];
                int col = c0f4 * 4 + cc * 32;
                dst[col + 0] = f2bf(x.x);
                dst[col + 1] = f2bf(x.y);
                dst[col + 2] = f2bf(x.z);
                dst[col + 3] = f2bf(x.w);
            }
        }
    }

    f32x4 acc[16];

    // ---- up-proj: K=128, N=256, bias, no activation ----
    #pragma unroll
    for (int nt = 0; nt < 16; ++nt) acc[nt] = (f32x4){0.f, 0.f, 0.f, 0.f};

    #pragma unroll
    for (int ks = 0; ks < 4; ++ks) {
        bf16x8 a = *(const bf16x8*)&act[(m0 + ln15) * LDA + ks * 32 + kq * 8];
        const unsigned short* wb = wup + ln15 * HIDDEN + ks * 32 + kq * 8;
        #pragma unroll
        for (int nt = 0; nt < 16; ++nt) {
            bf16x8 b = *(const bf16x8*)(wb + nt * 16 * HIDDEN);
            acc[nt] = __builtin_amdgcn_mfma_f32_16x16x32_bf16(a, b, acc[nt], 0, 0, 0);
        }
    }
    #pragma unroll
    for (int nt = 0; nt < 16; ++nt) {
        int n = nt * 16 + ln15;
        float bias = bup[n];
        #pragma unroll
        for (int r = 0; r < 4; ++r) {
            int row = m0 + kq * 4 + r;
            act[row * LDA + n] = f2bf(acc[nt][r] + bias);
        }
    }

    // ---- 3 hidden layers: K=256, N=256, bias + SiLU ----
    for (int l = 0; l < NLAYERS; ++l) {
        const unsigned short* W = wsl + l * OUT_EMB * OUT_EMB;
        const float* bias_l = bs + l * OUT_EMB;

        #pragma unroll
        for (int nt = 0; nt < 16; ++nt) acc[nt] = (f32x4){0.f, 0.f, 0.f, 0.f};

        #pragma unroll
        for (int ks = 0; ks < 8; ++ks) {
            bf16x8 a = *(const bf16x8*)&act[(m0 + ln15) * LDA + ks * 32 + kq * 8];
            const unsigned short* wb = W + ln15 * OUT_EMB + ks * 32 + kq * 8;
            #pragma unroll
            for (int nt = 0; nt < 16; ++nt) {
                bf16x8 b = *(const bf16x8*)(wb + nt * 16 * OUT_EMB);
                acc[nt] = __builtin_amdgcn_mfma_f32_16x16x32_bf16(a, b, acc[nt], 0, 0, 0);
            }
        }
        #pragma unroll
        for (int nt = 0; nt < 16; ++nt) {
            int n = nt * 16 + ln15;
            float bias = bias_l[n];
            #pragma unroll
            for (int r = 0; r < 4; ++r) {
                float x = acc[nt][r] + bias;
                float s = x / (1.f + __expf(-x));   // SiLU in fp32
                int row = m0 + kq * 4 + r;
                act[row * LDA + n] = f2bf(s);
            }
        }
    }

    // ---- output: out[m] = act[m] . wout ; 4 lanes per row ----
    {
        int r = tid >> 2;          // 0..63  (rows 16w..16w+15 stay wave-private)
        int part = tid & 3;
        const unsigned short* arow = &act[r * LDA + part * 64];
        const float* wrow = wout + part * 64;
        float s = 0.f;
        #pragma unroll
        for (int j = 0; j < 64; ++j) s += bf2f(arow[j]) * wrow[j];
        s += __shfl_xor(s, 1);
        s += __shfl_xor(s, 2);
        long long rowg = rowbase + r;
        if (part == 0 && rowg < M) out[rowg] = s;
    }
}

extern "C" void kernel_launch(void* const* d_in, const int* in_sizes, int n_in,
                              void* d_out, int out_size, void* d_ws, size_t ws_size,
                              hipStream_t stream) {
    const float* e2    = (const float*)d_in[0];
    const int*   idx   = (const int*)d_in[1];
    const float* W_up  = (const float*)d_in[2];
    const float* b_up  = (const float*)d_in[3];
    const float* Ws    = (const float*)d_in[4];
    const float* bs    = (const float*)d_in[5];
    const float* W_out = (const float*)d_in[6];

    const int num_edges = in_sizes[0] / HIDDEN;
    const int M = out_size;                       // 50000 nodes, OUT_CH=1
    const int Mpad = ((M + TM - 1) / TM) * TM;

    float* v = (float*)d_ws;
    size_t vbytes = (size_t)Mpad * HIDDEN * sizeof(float);
    unsigned short* wup_bf = (unsigned short*)((char*)d_ws + vbytes);
    unsigned short* wsl_bf = wup_bf + OUT_EMB * HIDDEN;

    // zero node accumulator (ws is poisoned 0xAA each call)
    hipMemsetAsync(d_ws, 0, vbytes, stream);

    // weights -> bf16
    {
        int total = OUT_EMB * HIDDEN + NLAYERS * OUT_EMB * OUT_EMB;
        convert_kernel<<<(total + 255) / 256, 256, 0, stream>>>(W_up, Ws, wup_bf, wsl_bf);
    }

    // scatter-sum
    {
        long long threads = (long long)num_edges * 32;
        int blocks = (int)((threads + 255) / 256);
        scatter_kernel<<<blocks, 256, 0, stream>>>(e2, idx, v, num_edges);
    }

    // fused MLP
    mlp_kernel<<<Mpad / TM, 256, 0, stream>>>(v, wup_bf, b_up, wsl_bf, bs, W_out,
                                              (float*)d_out, M);
}

// Round 2
// 1001.009 us; speedup vs baseline: 2.4887x; 2.4887x over previous
//
#include <hip/hip_runtime.h>

#define HIDDEN 128
#define OUT_EMB 256
#define NLAYERS 3
#define TM 64
#define LDA 264   // LDS row stride in bf16 elements (256 + 8 pad)

typedef __bf16 bf16x8 __attribute__((ext_vector_type(8)));
typedef float f32x4 __attribute__((ext_vector_type(4)));

__device__ __forceinline__ unsigned short f2bf(float x) {
    union { float f; unsigned u; } c; c.f = x;
    unsigned r = c.u + 0x7fff + ((c.u >> 16) & 1);
    return (unsigned short)(r >> 16);
}
__device__ __forceinline__ float bf2f(unsigned short h) {
    union { unsigned u; float f; } c; c.u = ((unsigned)h) << 16;
    return c.f;
}

// ---------------- CSR build ----------------
__global__ __launch_bounds__(256) void hist_kernel(
    const int* __restrict__ idx, int* __restrict__ counts, int ne)
{
    int e = blockIdx.x * 256 + threadIdx.x;
    if (e < ne) atomicAdd(&counts[idx[e]], 1);
}

__global__ __launch_bounds__(1024) void scan_kernel(
    const int* __restrict__ counts, int* __restrict__ offsets,
    int* __restrict__ cursor, int n)
{
    __shared__ int part[1024];
    int t = threadIdx.x;
    int chunk = (n + 1023) >> 10;
    int lo = t * chunk;
    int hi = lo + chunk; if (hi > n) hi = n;
    int s = 0;
    for (int i = lo; i < hi; ++i) s += counts[i];
    part[t] = s;
    __syncthreads();
    for (int off = 1; off < 1024; off <<= 1) {
        int v = (t >= off) ? part[t - off] : 0;
        __syncthreads();
        part[t] += v;
        __syncthreads();
    }
    int base = (t > 0) ? part[t - 1] : 0;
    for (int i = lo; i < hi; ++i) {
        offsets[i] = base;
        cursor[i]  = base;
        base += counts[i];
    }
}

__global__ __launch_bounds__(256) void fill_kernel(
    const int* __restrict__ idx, int* __restrict__ cursor,
    int* __restrict__ edge_list, int ne)
{
    int e = blockIdx.x * 256 + threadIdx.x;
    if (e < ne) {
        int pos = atomicAdd(&cursor[idx[e]], 1);
        edge_list[pos] = e;
    }
}

// ---------------- gather-reduce: v_bf[n] = sum over edges of node n ----------------
// one wave per node; lane handles 2 columns (float2)
__global__ __launch_bounds__(256) void gather_kernel(
    const float* __restrict__ e2, const int* __restrict__ edge_list,
    const int* __restrict__ offsets, const int* __restrict__ counts,
    unsigned short* __restrict__ vbf, int Mpad)
{
    int node = blockIdx.x * 4 + (threadIdx.x >> 6);
    if (node >= Mpad) return;
    int lane = threadIdx.x & 63;
    int start = offsets[node];
    int cnt   = counts[node];
    float ax = 0.f, ay = 0.f;
    const float* base = e2 + lane * 2;
    int j = 0;
    for (; j + 1 < cnt; j += 2) {
        int e0 = edge_list[start + j];
        int e1 = edge_list[start + j + 1];
        float2 x0 = *(const float2*)(base + (long long)e0 * HIDDEN);
        float2 x1 = *(const float2*)(base + (long long)e1 * HIDDEN);
        ax += x0.x + x1.x;
        ay += x0.y + x1.y;
    }
    if (j < cnt) {
        int e0 = edge_list[start + j];
        float2 x0 = *(const float2*)(base + (long long)e0 * HIDDEN);
        ax += x0.x; ay += x0.y;
    }
    unsigned p = ((unsigned)f2bf(ay) << 16) | (unsigned)f2bf(ax);
    *(unsigned*)(vbf + (long long)node * HIDDEN + lane * 2) = p;
}

// ---------------- weight fp32 -> bf16 ----------------
__global__ __launch_bounds__(256) void convert_kernel(
    const float* __restrict__ wup_f, const float* __restrict__ ws_f,
    unsigned short* __restrict__ wup, unsigned short* __restrict__ wsl)
{
    int t = blockIdx.x * blockDim.x + threadIdx.x;
    const int n1 = OUT_EMB * HIDDEN;
    const int n2 = NLAYERS * OUT_EMB * OUT_EMB;
    if (t < n1) wup[t] = f2bf(wup_f[t]);
    else if (t < n1 + n2) wsl[t - n1] = f2bf(ws_f[t - n1]);
}

// ---------------- fused MLP ----------------
// block = 64 rows; 4 waves; wave wv owns cols [wv*64, wv*64+64) (4 n-tiles),
// computes all 4 m-tiles -> B-frags reused 4x, 4x less weight traffic per wave.
// Single LDS act buffer: all reads happen in MFMA phase, barrier, then writes.
__global__ __launch_bounds__(256) void mlp_kernel(
    const unsigned short* __restrict__ vbf,   // [Mpad][128] bf16
    const unsigned short* __restrict__ wup,   // [256][128] bf16
    const float* __restrict__ bup,            // [256]
    const unsigned short* __restrict__ wsl,   // [3][256][256] bf16
    const float* __restrict__ bs,             // [3][256]
    const float* __restrict__ wout,           // [256] fp32
    float* __restrict__ out, int M)
{
    __shared__ unsigned short act[TM * LDA];

    const int tid  = threadIdx.x;
    const int wv   = tid >> 6;
    const int lane = tid & 63;
    const int ln15 = lane & 15;
    const int kq   = lane >> 4;          // 0..3
    const int n0   = wv * 64;
    const long long rowbase = (long long)blockIdx.x * TM;

    f32x4 acc[4][4];

    // ---- up-proj: K=128, A straight from global bf16 v ----
    #pragma unroll
    for (int mt = 0; mt < 4; ++mt)
        #pragma unroll
        for (int nt = 0; nt < 4; ++nt)
            acc[mt][nt] = (f32x4){0.f, 0.f, 0.f, 0.f};

    #pragma unroll
    for (int ks = 0; ks < 4; ++ks) {
        bf16x8 a[4], b[4];
        #pragma unroll
        for (int mt = 0; mt < 4; ++mt)
            a[mt] = *(const bf16x8*)&vbf[(rowbase + mt * 16 + ln15) * HIDDEN + ks * 32 + kq * 8];
        #pragma unroll
        for (int nt = 0; nt < 4; ++nt)
            b[nt] = *(const bf16x8*)&wup[(n0 + nt * 16 + ln15) * HIDDEN + ks * 32 + kq * 8];
        #pragma unroll
        for (int mt = 0; mt < 4; ++mt)
            #pragma unroll
            for (int nt = 0; nt < 4; ++nt)
                acc[mt][nt] = __builtin_amdgcn_mfma_f32_16x16x32_bf16(a[mt], b[nt], acc[mt][nt], 0, 0, 0);
    }
    #pragma unroll
    for (int nt = 0; nt < 4; ++nt) {
        int n = n0 + nt * 16 + ln15;
        float bias = bup[n];
        #pragma unroll
        for (int mt = 0; mt < 4; ++mt)
            #pragma unroll
            for (int r = 0; r < 4; ++r)
                act[(mt * 16 + kq * 4 + r) * LDA + n] = f2bf(acc[mt][nt][r] + bias);
    }
    __syncthreads();

    // ---- 3 hidden layers: K=256, bias + SiLU ----
    for (int l = 0; l < NLAYERS; ++l) {
        const unsigned short* W = wsl + l * OUT_EMB * OUT_EMB;
        const float* bias_l = bs + l * OUT_EMB;

        #pragma unroll
        for (int mt = 0; mt < 4; ++mt)
            #pragma unroll
            for (int nt = 0; nt < 4; ++nt)
                acc[mt][nt] = (f32x4){0.f, 0.f, 0.f, 0.f};

        #pragma unroll
        for (int ks = 0; ks < 8; ++ks) {
            bf16x8 a[4], b[4];
            #pragma unroll
            for (int mt = 0; mt < 4; ++mt)
                a[mt] = *(const bf16x8*)&act[(mt * 16 + ln15) * LDA + ks * 32 + kq * 8];
            #pragma unroll
            for (int nt = 0; nt < 4; ++nt)
                b[nt] = *(const bf16x8*)&W[(n0 + nt * 16 + ln15) * OUT_EMB + ks * 32 + kq * 8];
            #pragma unroll
            for (int mt = 0; mt < 4; ++mt)
                #pragma unroll
                for (int nt = 0; nt < 4; ++nt)
                    acc[mt][nt] = __builtin_amdgcn_mfma_f32_16x16x32_bf16(a[mt], b[nt], acc[mt][nt], 0, 0, 0);
        }
        __syncthreads();   // all LDS reads complete before overwrite
        #pragma unroll
        for (int nt = 0; nt < 4; ++nt) {
            int n = n0 + nt * 16 + ln15;
            float bias = bias_l[n];
            #pragma unroll
            for (int mt = 0; mt < 4; ++mt)
                #pragma unroll
                for (int r = 0; r < 4; ++r) {
                    float x = acc[mt][nt][r] + bias;
                    float s = x / (1.f + __expf(-x));   // SiLU fp32
                    act[(mt * 16 + kq * 4 + r) * LDA + n] = f2bf(s);
                }
        }
        __syncthreads();
    }

    // ---- output: out[m] = act[m] . wout ; 4 lanes per row ----
    {
        int r = tid >> 2;
        int part = tid & 3;
        const unsigned short* arow = &act[r * LDA + part * 64];
        const float* wrow = wout + part * 64;
        float s = 0.f;
        #pragma unroll
        for (int jj = 0; jj < 64; ++jj) s += bf2f(arow[jj]) * wrow[jj];
        s += __shfl_xor(s, 1);
        s += __shfl_xor(s, 2);
        long long rowg = rowbase + r;
        if (part == 0 && rowg < M) out[rowg] = s;
    }
}

extern "C" void kernel_launch(void* const* d_in, const int* in_sizes, int n_in,
                              void* d_out, int out_size, void* d_ws, size_t ws_size,
                              hipStream_t stream) {
    const float* e2    = (const float*)d_in[0];
    const int*   idx   = (const int*)d_in[1];
    const float* W_up  = (const float*)d_in[2];
    const float* b_up  = (const float*)d_in[3];
    const float* Ws    = (const float*)d_in[4];
    const float* bs    = (const float*)d_in[5];
    const float* W_out = (const float*)d_in[6];

    const int ne = in_sizes[0] / HIDDEN;
    const int M  = out_size;                      // 50000
    const int Mpad = ((M + TM - 1) / TM) * TM;    // 50048

    char* p = (char*)d_ws;
    unsigned short* vbf    = (unsigned short*)p;  p += (size_t)Mpad * HIDDEN * 2;
    unsigned short* wup_bf = (unsigned short*)p;  p += (size_t)OUT_EMB * HIDDEN * 2;
    unsigned short* wsl_bf = (unsigned short*)p;  p += (size_t)NLAYERS * OUT_EMB * OUT_EMB * 2;
    int* counts    = (int*)p;  p += (size_t)Mpad * 4;
    int* offsets   = (int*)p;  p += (size_t)Mpad * 4;
    int* cursor    = (int*)p;  p += (size_t)Mpad * 4;
    int* edge_list = (int*)p;  p += (size_t)ne * 4;

    hipMemsetAsync(counts, 0, (size_t)Mpad * 4, stream);

    hist_kernel<<<(ne + 255) / 256, 256, 0, stream>>>(idx, counts, ne);
    scan_kernel<<<1, 1024, 0, stream>>>(counts, offsets, cursor, Mpad);
    fill_kernel<<<(ne + 255) / 256, 256, 0, stream>>>(idx, cursor, edge_list, ne);

    {
        int total = OUT_EMB * HIDDEN + NLAYERS * OUT_EMB * OUT_EMB;
        convert_kernel<<<(total + 255) / 256, 256, 0, stream>>>(W_up, Ws, wup_bf, wsl_bf);
    }

    gather_kernel<<<(Mpad + 3) / 4, 256, 0, stream>>>(e2, edge_list, offsets, counts, vbf, Mpad);

    mlp_kernel<<<Mpad / TM, 256, 0, stream>>>(vbf, wup_bf, b_up, wsl_bf, bs, W_out,
                                              (float*)d_out, M);
}

// Round 3
// 890.534 us; speedup vs baseline: 2.7975x; 1.1241x over previous
//
#include <hip/hip_runtime.h>

#define HIDDEN 128
#define OUT_EMB 256
#define NLAYERS 3
#define TM 64
#define LDA 264   // LDS row stride in bf16 elements (256 + 8 pad)

typedef __bf16 bf16x8 __attribute__((ext_vector_type(8)));
typedef float f32x4 __attribute__((ext_vector_type(4)));

__device__ __forceinline__ unsigned short f2bf(float x) {
    union { float f; unsigned u; } c; c.f = x;
    unsigned r = c.u + 0x7fff + ((c.u >> 16) & 1);
    return (unsigned short)(r >> 16);
}
__device__ __forceinline__ float bf2f(unsigned short h) {
    union { unsigned u; float f; } c; c.u = ((unsigned)h) << 16;
    return c.f;
}

// ---------------- CSR build ----------------
__global__ __launch_bounds__(256) void hist_kernel(
    const int* __restrict__ idx, int* __restrict__ counts, int ne)
{
    int e = blockIdx.x * 256 + threadIdx.x;
    if (e < ne) atomicAdd(&counts[idx[e]], 1);
}

// 3-kernel parallel exclusive scan over counts[n]
__global__ __launch_bounds__(256) void scan1_kernel(
    const int* __restrict__ counts, int* __restrict__ bsum, int n)
{
    __shared__ int sh[256];
    int t = threadIdx.x;
    int i = blockIdx.x * 256 + t;
    sh[t] = (i < n) ? counts[i] : 0;
    __syncthreads();
    for (int off = 128; off > 0; off >>= 1) {
        if (t < off) sh[t] += sh[t + off];
        __syncthreads();
    }
    if (t == 0) bsum[blockIdx.x] = sh[0];
}

__global__ __launch_bounds__(256) void scan2_kernel(
    int* __restrict__ bsum, int* __restrict__ boff, int nb)
{
    __shared__ int sh[256];
    int t = threadIdx.x;
    int v = (t < nb) ? bsum[t] : 0;
    sh[t] = v;
    __syncthreads();
    for (int off = 1; off < 256; off <<= 1) {
        int u = (t >= off) ? sh[t - off] : 0;
        __syncthreads();
        sh[t] += u;
        __syncthreads();
    }
    if (t < nb) boff[t] = sh[t] - v;   // exclusive
}

__global__ __launch_bounds__(256) void scan3_kernel(
    const int* __restrict__ counts, const int* __restrict__ boff,
    int* __restrict__ offsets, int* __restrict__ cursor, int n)
{
    __shared__ int sh[256];
    int t = threadIdx.x;
    int i = blockIdx.x * 256 + t;
    int v = (i < n) ? counts[i] : 0;
    sh[t] = v;
    __syncthreads();
    for (int off = 1; off < 256; off <<= 1) {
        int u = (t >= off) ? sh[t - off] : 0;
        __syncthreads();
        sh[t] += u;
        __syncthreads();
    }
    if (i < n) {
        int excl = boff[blockIdx.x] + sh[t] - v;
        offsets[i] = excl;
        cursor[i]  = excl;
    }
}

__global__ __launch_bounds__(256) void fill_kernel(
    const int* __restrict__ idx, int* __restrict__ cursor,
    int* __restrict__ edge_list, int ne)
{
    int e = blockIdx.x * 256 + threadIdx.x;
    if (e < ne) {
        int pos = atomicAdd(&cursor[idx[e]], 1);
        edge_list[pos] = e;
    }
}

// ---------------- gather-reduce ----------------
// one wave per node; half-wave per edge (lane&31 covers 4 cols via float4);
// 2 edges per iter, unrolled x2 -> 4 edges in flight.
__global__ __launch_bounds__(256) void gather_kernel(
    const float* __restrict__ e2, const int* __restrict__ edge_list,
    const int* __restrict__ offsets, const int* __restrict__ counts,
    unsigned short* __restrict__ vbf, int Mpad)
{
    int node = blockIdx.x * 4 + (threadIdx.x >> 6);
    if (node >= Mpad) return;
    int lane = threadIdx.x & 63;
    int half = lane >> 5;            // 0 or 1
    int c4   = lane & 31;            // float4 index within row
    int start = offsets[node];
    int cnt   = counts[node];

    f32x4 a0 = {0.f, 0.f, 0.f, 0.f};
    f32x4 a1 = {0.f, 0.f, 0.f, 0.f};

    int j = 0;
    for (; j + 4 <= cnt; j += 4) {
        int e0 = edge_list[start + j + half];
        int e1 = edge_list[start + j + 2 + half];
        f32x4 x0 = *(const f32x4*)(e2 + (long long)e0 * HIDDEN + c4 * 4);
        f32x4 x1 = *(const f32x4*)(e2 + (long long)e1 * HIDDEN + c4 * 4);
        a0 += x0;
        a1 += x1;
    }
    for (; j + 2 <= cnt; j += 2) {
        int e0 = edge_list[start + j + half];
        f32x4 x0 = *(const f32x4*)(e2 + (long long)e0 * HIDDEN + c4 * 4);
        a0 += x0;
    }
    if (j < cnt && half == 0) {
        int e0 = edge_list[start + j];
        f32x4 x0 = *(const f32x4*)(e2 + (long long)e0 * HIDDEN + c4 * 4);
        a1 += x0;
    }
    a0 += a1;
    // combine halves
    a0[0] += __shfl_xor(a0[0], 32);
    a0[1] += __shfl_xor(a0[1], 32);
    a0[2] += __shfl_xor(a0[2], 32);
    a0[3] += __shfl_xor(a0[3], 32);

    if (half == 0) {
        unsigned lo = (unsigned)f2bf(a0[0]) | ((unsigned)f2bf(a0[1]) << 16);
        unsigned hi = (unsigned)f2bf(a0[2]) | ((unsigned)f2bf(a0[3]) << 16);
        uint2 p; p.x = lo; p.y = hi;
        *(uint2*)(vbf + (long long)node * HIDDEN + c4 * 4) = p;
    }
}

// ---------------- weight fp32 -> bf16 ----------------
__global__ __launch_bounds__(256) void convert_kernel(
    const float* __restrict__ wup_f, const float* __restrict__ ws_f,
    unsigned short* __restrict__ wup, unsigned short* __restrict__ wsl)
{
    int t = blockIdx.x * blockDim.x + threadIdx.x;
    const int n1 = OUT_EMB * HIDDEN;
    const int n2 = NLAYERS * OUT_EMB * OUT_EMB;
    if (t < n1) wup[t] = f2bf(wup_f[t]);
    else if (t < n1 + n2) wsl[t - n1] = f2bf(ws_f[t - n1]);
}

// ---------------- fused MLP (unchanged from R2: passed, absmax .047) ----------------
__global__ __launch_bounds__(256) void mlp_kernel(
    const unsigned short* __restrict__ vbf,   // [Mpad][128] bf16
    const unsigned short* __restrict__ wup,   // [256][128] bf16
    const float* __restrict__ bup,            // [256]
    const unsigned short* __restrict__ wsl,   // [3][256][256] bf16
    const float* __restrict__ bs,             // [3][256]
    const float* __restrict__ wout,           // [256] fp32
    float* __restrict__ out, int M)
{
    __shared__ unsigned short act[TM * LDA];

    const int tid  = threadIdx.x;
    const int wv   = tid >> 6;
    const int lane = tid & 63;
    const int ln15 = lane & 15;
    const int kq   = lane >> 4;
    const int n0   = wv * 64;
    const long long rowbase = (long long)blockIdx.x * TM;

    f32x4 acc[4][4];

    #pragma unroll
    for (int mt = 0; mt < 4; ++mt)
        #pragma unroll
        for (int nt = 0; nt < 4; ++nt)
            acc[mt][nt] = (f32x4){0.f, 0.f, 0.f, 0.f};

    #pragma unroll
    for (int ks = 0; ks < 4; ++ks) {
        bf16x8 a[4], b[4];
        #pragma unroll
        for (int mt = 0; mt < 4; ++mt)
            a[mt] = *(const bf16x8*)&vbf[(rowbase + mt * 16 + ln15) * HIDDEN + ks * 32 + kq * 8];
        #pragma unroll
        for (int nt = 0; nt < 4; ++nt)
            b[nt] = *(const bf16x8*)&wup[(n0 + nt * 16 + ln15) * HIDDEN + ks * 32 + kq * 8];
        #pragma unroll
        for (int mt = 0; mt < 4; ++mt)
            #pragma unroll
            for (int nt = 0; nt < 4; ++nt)
                acc[mt][nt] = __builtin_amdgcn_mfma_f32_16x16x32_bf16(a[mt], b[nt], acc[mt][nt], 0, 0, 0);
    }
    #pragma unroll
    for (int nt = 0; nt < 4; ++nt) {
        int n = n0 + nt * 16 + ln15;
        float bias = bup[n];
        #pragma unroll
        for (int mt = 0; mt < 4; ++mt)
            #pragma unroll
            for (int r = 0; r < 4; ++r)
                act[(mt * 16 + kq * 4 + r) * LDA + n] = f2bf(acc[mt][nt][r] + bias);
    }
    __syncthreads();

    for (int l = 0; l < NLAYERS; ++l) {
        const unsigned short* W = wsl + l * OUT_EMB * OUT_EMB;
        const float* bias_l = bs + l * OUT_EMB;

        #pragma unroll
        for (int mt = 0; mt < 4; ++mt)
            #pragma unroll
            for (int nt = 0; nt < 4; ++nt)
                acc[mt][nt] = (f32x4){0.f, 0.f, 0.f, 0.f};

        #pragma unroll
        for (int ks = 0; ks < 8; ++ks) {
            bf16x8 a[4], b[4];
            #pragma unroll
            for (int mt = 0; mt < 4; ++mt)
                a[mt] = *(const bf16x8*)&act[(mt * 16 + ln15) * LDA + ks * 32 + kq * 8];
            #pragma unroll
            for (int nt = 0; nt < 4; ++nt)
                b[nt] = *(const bf16x8*)&W[(n0 + nt * 16 + ln15) * OUT_EMB + ks * 32 + kq * 8];
            #pragma unroll
            for (int mt = 0; mt < 4; ++mt)
                #pragma unroll
                for (int nt = 0; nt < 4; ++nt)
                    acc[mt][nt] = __builtin_amdgcn_mfma_f32_16x16x32_bf16(a[mt], b[nt], acc[mt][nt], 0, 0, 0);
        }
        __syncthreads();
        #pragma unroll
        for (int nt = 0; nt < 4; ++nt) {
            int n = n0 + nt * 16 + ln15;
            float bias = bias_l[n];
            #pragma unroll
            for (int mt = 0; mt < 4; ++mt)
                #pragma unroll
                for (int r = 0; r < 4; ++r) {
                    float x = acc[mt][nt][r] + bias;
                    float s = x / (1.f + __expf(-x));
                    act[(mt * 16 + kq * 4 + r) * LDA + n] = f2bf(s);
                }
        }
        __syncthreads();
    }

    {
        int r = tid >> 2;
        int part = tid & 3;
        const unsigned short* arow = &act[r * LDA + part * 64];
        const float* wrow = wout + part * 64;
        float s = 0.f;
        #pragma unroll
        for (int jj = 0; jj < 64; ++jj) s += bf2f(arow[jj]) * wrow[jj];
        s += __shfl_xor(s, 1);
        s += __shfl_xor(s, 2);
        long long rowg = rowbase + r;
        if (part == 0 && rowg < M) out[rowg] = s;
    }
}

extern "C" void kernel_launch(void* const* d_in, const int* in_sizes, int n_in,
                              void* d_out, int out_size, void* d_ws, size_t ws_size,
                              hipStream_t stream) {
    const float* e2    = (const float*)d_in[0];
    const int*   idx   = (const int*)d_in[1];
    const float* W_up  = (const float*)d_in[2];
    const float* b_up  = (const float*)d_in[3];
    const float* Ws    = (const float*)d_in[4];
    const float* bs    = (const float*)d_in[5];
    const float* W_out = (const float*)d_in[6];

    const int ne = in_sizes[0] / HIDDEN;
    const int M  = out_size;                      // 50000
    const int Mpad = ((M + TM - 1) / TM) * TM;    // 50048
    const int nb = (Mpad + 255) / 256;            // 196 scan blocks

    char* p = (char*)d_ws;
    unsigned short* vbf    = (unsigned short*)p;  p += (size_t)Mpad * HIDDEN * 2;
    unsigned short* wup_bf = (unsigned short*)p;  p += (size_t)OUT_EMB * HIDDEN * 2;
    unsigned short* wsl_bf = (unsigned short*)p;  p += (size_t)NLAYERS * OUT_EMB * OUT_EMB * 2;
    int* counts    = (int*)p;  p += (size_t)Mpad * 4;
    int* offsets   = (int*)p;  p += (size_t)Mpad * 4;
    int* cursor    = (int*)p;  p += (size_t)Mpad * 4;
    int* bsum      = (int*)p;  p += 256 * 4;
    int* boff      = (int*)p;  p += 256 * 4;
    int* edge_list = (int*)p;  p += (size_t)ne * 4;

    hipMemsetAsync(counts, 0, (size_t)Mpad * 4, stream);

    hist_kernel <<<(ne + 255) / 256, 256, 0, stream>>>(idx, counts, ne);
    scan1_kernel<<<nb, 256, 0, stream>>>(counts, bsum, Mpad);
    scan2_kernel<<<1, 256, 0, stream>>>(bsum, boff, nb);
    scan3_kernel<<<nb, 256, 0, stream>>>(counts, boff, offsets, cursor, Mpad);
    fill_kernel <<<(ne + 255) / 256, 256, 0, stream>>>(idx, cursor, edge_list, ne);

    {
        int total = OUT_EMB * HIDDEN + NLAYERS * OUT_EMB * OUT_EMB;
        convert_kernel<<<(total + 255) / 256, 256, 0, stream>>>(W_up, Ws, wup_bf, wsl_bf);
    }

    gather_kernel<<<(Mpad + 3) / 4, 256, 0, stream>>>(e2, edge_list, offsets, counts, vbf, Mpad);

    mlp_kernel<<<Mpad / TM, 256, 0, stream>>>(vbf, wup_bf, b_up, wsl_bf, bs, W_out,
                                              (float*)d_out, M);
}